// Round 6
// baseline (124.448 us; speedup 1.0000x reference)
//
#include <hip/hip_runtime.h>

// Problem constants
static constexpr int NQ    = 12;
static constexpr int DEPTH = 4;
static constexpr int LAT   = 512;
static constexpr int FAST  = DEPTH * NQ;   // 48
static constexpr float DECAY = 0.9f;

using v2f = __attribute__((ext_vector_type(2))) float;

// r20: r19's verified algorithm (layout role-swap reg h = wires 0..5 /
// lane l = wires 6..11; sigma = G6 reg-rename + 2-index bperm lane pull;
// permlane sum-form wires 6/7; DPP wires 8..11; register butterflies 0..5)
// at ONE ELEMENT PER WAVE, 2048 blocks.
// Rationale: r14-r19 all land at 48-58us with VALU<=45%, DS<=30%, occupancy
// 10% (= 1 wave/SIMD; grid 1024 waves on 1024 SIMDs). The residual ~55% idle
// is PRIVATE dependency latency (bperm lgkm waits, DPP->FMA chains, trig) --
// hidden only by a co-resident wave. 1 elem/wave doubles waves to 2048 ->
// 2 waves/SIMD, halves per-wave work; per-SIMD VALU work unchanged but two
// independent streams interleave. (r15's null result came from its shared
// LDS-convoy walls, which r19's structure eliminated: DS/layer = 64 bperm.)

__device__ __forceinline__ constexpr int G6(int x){ return (x ^ (x >> 1)) & 63; }

__device__ __forceinline__ float bperm(int idx, float v){
    return __int_as_float(__builtin_amdgcn_ds_bpermute(idx, __float_as_int(v)));
}
template<int CTRL>
__device__ __forceinline__ float dppf(float x){
    return __int_as_float(__builtin_amdgcn_mov_dpp(__float_as_int(x), CTRL, 0xF, 0xF, false));
}
// x[l] + x[l^32]  (direction-proof sum form, r19-verified)
__device__ __forceinline__ float xsum32(float x){
    float a = x, b = x;
    asm("v_permlane32_swap_b32 %0, %1" : "+v"(a), "+v"(b));
    return a + b;
}
// x[l] + x[l^16]  (r19-verified)
__device__ __forceinline__ float xsum16(float x){
    float a = x, b = x;
    asm("v_permlane16_swap_b32 %0, %1" : "+v"(a), "+v"(b));
    return a + b;
}

// ---------------- r14-verified register butterflies (wires 0..5) ----------
template<int S, int B>
__device__ __forceinline__ void bfly_half(float (&v)[64], float c, float s) {
    v2f c2 = {c, c}, s2 = {s, s};
    #pragma unroll
    for (int r0 = B; r0 < B + 32; r0 += 2) {
        if ((r0 & S) == 0) {
            v2f a = {v[r0],     v[r0 + 1]};
            v2f b = {v[r0 + S], v[r0 + S + 1]};
            v2f na = c2 * a - s2 * b;
            v2f nb = s2 * a + c2 * b;
            v[r0]     = na.x;  v[r0 + 1]     = na.y;
            v[r0 + S] = nb.x;  v[r0 + S + 1] = nb.y;
        }
    }
}
template<int B>
__device__ __forceinline__ void bfly1_half(float (&v)[64], float c, float s) {
    v2f cs = {c, s}, nsc = {-s, c};
    #pragma unroll
    for (int r0 = B; r0 < B + 32; r0 += 2) {
        float a = v[r0], b = v[r0 + 1];
        v2f aa = {a, a}, bb = {b, b};
        v2f res = cs * aa + nsc * bb;   // (c*a - s*b, s*a + c*b)
        v[r0]     = res.x;
        v[r0 + 1] = res.y;
    }
}
template<int B>
__device__ __forceinline__ void ry5_half(float (&v)[64], const v2f* cs) {
    bfly_half<16, B>(v, cs[0].x, cs[0].y);
    bfly_half<8,  B>(v, cs[1].x, cs[1].y);
    bfly_half<4,  B>(v, cs[2].x, cs[2].y);
    bfly_half<2,  B>(v, cs[3].x, cs[3].y);
    bfly1_half<B>(v, cs[4].x, cs[4].y);
}
__device__ __forceinline__ void bfly32(float (&v)[64], float c, float s) {
    v2f c2 = {c, c}, s2 = {s, s};
    #pragma unroll
    for (int r0 = 0; r0 < 32; r0 += 2) {
        v2f a = {v[r0],      v[r0 + 1]};
        v2f b = {v[r0 + 32], v[r0 + 33]};
        v2f na = c2 * a - s2 * b;
        v2f nb = s2 * a + c2 * b;
        v[r0]      = na.x;  v[r0 + 1]  = na.y;
        v[r0 + 32] = nb.x;  v[r0 + 33] = nb.y;
    }
}
// wires 0..5: cs[0] = stride-32 (wire0) ... cs[5] = stride-1 (wire5)
__device__ __forceinline__ void ry6(float (&v)[64], const v2f* cs) {
    ry5_half<0>(v, cs + 1);
    ry5_half<32>(v, cs + 1);
    bfly32(v, cs[0].x, cs[0].y);
}

// product state; lane = low 6 amp bits (wires 6..11), reg h = wires 0..5
// [r18-verified]
__device__ __forceinline__ void init_state(float (&v)[64], const float (&xa)[NQ], int lane) {
    float g0[NQ], g1[NQ];
    #pragma unroll
    for (int w = 0; w < NQ; w++) {
        float hh = 0.5f * xa[w];
        float c = __cosf(hh), s = __sinf(hh);
        g0[w] = (c - s) * 0.70710678118654752f;
        g1[w] = (c + s) * 0.70710678118654752f;
    }
    float L = 1.0f;
    #pragma unroll
    for (int w = 6; w < NQ; w++)
        L *= ((lane >> (11 - w)) & 1) ? g1[w] : g0[w];
    v[0] = L;
    #pragma unroll
    for (int w = 0; w < 6; w++) {
        const int S = 32 >> w;
        #pragma unroll
        for (int r = 0; r < 64; r += 2 * S) {
            v[r + S] = v[r] * g1[w];
            v[r]     = v[r] * g0[w];
        }
    }
}

__global__ __launch_bounds__(64, 1)
void fwp_kernel(const float* __restrict__ x_t,
                const float* __restrict__ fast_prev,
                const float* __restrict__ W_enc,
                const float* __restrict__ b_enc,
                const float* __restrict__ W_upd,
                const float* __restrict__ b_upd,
                const float* __restrict__ W_ro,
                const float* __restrict__ b_ro,
                float* __restrict__ out_y,
                float* __restrict__ out_fast) {
    const int lane = threadIdx.x;          // block = one wave
    const int e    = blockIdx.x;           // ONE element per wave

    __shared__ __align__(16) float lat[LAT];   // 2 KB
    __shared__ __align__(8)  v2f   cs[FAST];   // 384 B

    // ---- x row (wave-uniform scalar loads, verified r7) ----
    float xa[NQ];
    #pragma unroll
    for (int k = 0; k < NQ; k++) xa[k] = x_t[e * NQ + k];

    // ---- Phase A: lane owns latents j = 8*lane..8*lane+7 (verified r13) ----
    {
        const float4* we = (const float4*)(W_enc + lane * 8 * NQ);  // 8 rows, 384 B
        float4 be0 = *(const float4*)&b_enc[8 * lane];
        float4 be1 = *(const float4*)&b_enc[8 * lane + 4];
        float be[8] = {be0.x, be0.y, be0.z, be0.w, be1.x, be1.y, be1.z, be1.w};
        float l[8];
        #pragma unroll
        for (int t = 0; t < 8; t++) {
            float4 a0 = we[3 * t], a1 = we[3 * t + 1], a2 = we[3 * t + 2];
            float s = be[t]
                + a0.x * xa[0] + a0.y * xa[1] + a0.z * xa[2]  + a0.w * xa[3]
                + a1.x * xa[4] + a1.y * xa[5] + a1.z * xa[6]  + a1.w * xa[7]
                + a2.x * xa[8] + a2.y * xa[9] + a2.z * xa[10] + a2.w * xa[11];
            l[t] = tanhf(s);
        }
        *(float4*)&lat[8 * lane]     = (float4){l[0], l[1], l[2], l[3]};
        *(float4*)&lat[8 * lane + 4] = (float4){l[4], l[5], l[6], l[7]};
    }

    // ---- Phase B: 48 angles; W_upd row loaded once per wave ----
    if (lane < FAST) {
        const float4* wr = (const float4*)(W_upd + lane * LAT);
        const float4* la = (const float4*)(lat);
        float s = b_upd[lane];
        #pragma unroll 8
        for (int j = 0; j < LAT / 4; j++) {
            float4 w4 = wr[j];
            float4 a4 = la[j];   // uniform -> broadcast
            s += w4.x * a4.x + w4.y * a4.y + w4.z * a4.z + w4.w * a4.w;
        }
        float ang = DECAY * fast_prev[e * FAST + lane] + s;
        out_fast[e * FAST + lane] = ang;
        cs[lane] = (v2f){__cosf(0.5f * ang), __sinf(0.5f * ang)};
    }

    // ---- product state (registers only) ----
    float u[64];
    init_state(u, xa, lane);

    // sigma lane-pull index vectors (bytes) [r18/r19-verified]
    const int idxA = G6(lane) * 4;           // h0 = 0
    const int idxB = idxA ^ 128;             // h0 = 1  (^32 lanes)

    #define SIG1(h, src) { const int idx_ = ((h) & 1) ? idxB : idxA; \
        u[h] = bperm(idx_, (src)); }

    // ---- 4 layers ----
    #pragma unroll 1
    for (int layer = 0; layer < DEPTH; layer++) {
        v2f c[NQ];
        #pragma unroll
        for (int w = 0; w < NQ; w++) c[w] = cs[layer * NQ + w];

        // -------- sigma: in-place along G6 register cycles [r19-verified] --------
        SIG1(0, u[0]);  SIG1(1, u[1]);
        { float t = u[2]; SIG1(2, u[3]); SIG1(3, t); }
        { float t = u[4]; SIG1(4, u[6]);  SIG1(6, u[5]);  SIG1(5, u[7]);  SIG1(7, t); }
        { float t = u[8]; SIG1(8, u[12]); SIG1(12, u[10]); SIG1(10, u[15]); SIG1(15, t); }
        { float t = u[9]; SIG1(9, u[13]); SIG1(13, u[11]); SIG1(11, u[14]); SIG1(14, t); }
        { float t = u[16]; SIG1(16, u[24]); SIG1(24, u[20]); SIG1(20, u[30]); SIG1(30, u[17]);
                           SIG1(17, u[25]); SIG1(25, u[21]); SIG1(21, u[31]); SIG1(31, t); }
        { float t = u[18]; SIG1(18, u[27]); SIG1(27, u[22]); SIG1(22, u[29]); SIG1(29, u[19]);
                           SIG1(19, u[26]); SIG1(26, u[23]); SIG1(23, u[28]); SIG1(28, t); }
        { float t = u[32]; SIG1(32, u[48]); SIG1(48, u[40]); SIG1(40, u[60]); SIG1(60, u[34]);
                           SIG1(34, u[51]); SIG1(51, u[42]); SIG1(42, u[63]); SIG1(63, t); }
        { float t = u[33]; SIG1(33, u[49]); SIG1(49, u[41]); SIG1(41, u[61]); SIG1(61, u[35]);
                           SIG1(35, u[50]); SIG1(50, u[43]); SIG1(43, u[62]); SIG1(62, t); }
        { float t = u[36]; SIG1(36, u[54]); SIG1(54, u[45]); SIG1(45, u[59]); SIG1(59, u[38]);
                           SIG1(38, u[53]); SIG1(53, u[47]); SIG1(47, u[56]); SIG1(56, t); }
        { float t = u[37]; SIG1(37, u[55]); SIG1(55, u[44]); SIG1(44, u[58]); SIG1(58, u[39]);
                           SIG1(39, u[52]); SIG1(52, u[46]); SIG1(46, u[57]); SIG1(57, t); }

        // -------- wire6: xor32 via permlane32 sum form [r19-verified] --------
        {
            float sv = (lane & 32) ? c[6].y : -c[6].y;
            float cm = c[6].x - sv;
            #pragma unroll
            for (int h = 0; h < 64; h++)
                u[h] = __builtin_fmaf(cm, u[h], sv * xsum32(u[h]));
        }
        // -------- wire7: xor16 via permlane16 sum form [r19-verified] --------
        {
            float sv = (lane & 16) ? c[7].y : -c[7].y;
            float cm = c[7].x - sv;
            #pragma unroll
            for (int h = 0; h < 64; h++)
                u[h] = __builtin_fmaf(cm, u[h], sv * xsum16(u[h]));
        }
        // -------- wire8: xor8 via DPP row_ror:8 [verified] --------
        {
            float sv = (lane & 8) ? c[8].y : -c[8].y;
            #pragma unroll
            for (int h = 0; h < 64; h++) {
                float p = dppf<0x128>(u[h]);
                u[h] = __builtin_fmaf(c[8].x, u[h], sv * p);
            }
        }
        // -------- wire9: xor4 = half_mirror o quad_perm[3,2,1,0] [verified] --------
        {
            float sv = (lane & 4) ? c[9].y : -c[9].y;
            #pragma unroll
            for (int h = 0; h < 64; h++) {
                float p = dppf<0x141>(dppf<0x1B>(u[h]));
                u[h] = __builtin_fmaf(c[9].x, u[h], sv * p);
            }
        }
        // -------- wire10: xor2 quad_perm[2,3,0,1] [verified] --------
        {
            float sv = (lane & 2) ? c[10].y : -c[10].y;
            #pragma unroll
            for (int h = 0; h < 64; h++) {
                float p = dppf<0x4E>(u[h]);
                u[h] = __builtin_fmaf(c[10].x, u[h], sv * p);
            }
        }
        // -------- wire11: xor1 quad_perm[1,0,3,2] [verified] --------
        {
            float sv = (lane & 1) ? c[11].y : -c[11].y;
            #pragma unroll
            for (int h = 0; h < 64; h++) {
                float p = dppf<0xB1>(u[h]);
                u[h] = __builtin_fmaf(c[11].x, u[h], sv * p);
            }
        }
        // -------- wires 0..5: register butterflies (r14-verified) --------
        ry6(u, c);
    }
    #undef SIG1

    // ---- Z expectations folded into readout (r18-verified mapping) ----
    float wro[NQ];
    #pragma unroll
    for (int w = 0; w < NQ; w++) wro[w] = W_ro[w];
    float sl = 0.0f;
    #pragma unroll
    for (int w = 6; w < NQ; w++)
        sl += ((lane >> (11 - w)) & 1) ? -wro[w] : wro[w];

    float tot = 0.0f, pw[6] = {0, 0, 0, 0, 0, 0};
    #pragma unroll
    for (int r = 0; r < 64; r++) {
        float p = u[r] * u[r];
        tot += p;
        pw[0] += (r & 32) ? -p : p;   // wire0 (reg bit5)
        pw[1] += (r & 16) ? -p : p;
        pw[2] += (r & 8)  ? -p : p;
        pw[3] += (r & 4)  ? -p : p;
        pw[4] += (r & 2)  ? -p : p;
        pw[5] += (r & 1)  ? -p : p;   // wire5 (reg bit0)
    }
    float y = sl * tot;
    #pragma unroll
    for (int k = 0; k < 6; k++) y += wro[k] * pw[k];
    #pragma unroll
    for (int m = 32; m >= 1; m >>= 1) y += __shfl_xor(y, m, 64);
    if (lane == 0) out_y[e] = y + b_ro[0];
}

extern "C" void kernel_launch(void* const* d_in, const int* in_sizes, int n_in,
                              void* d_out, int out_size, void* d_ws, size_t ws_size,
                              hipStream_t stream) {
    const float* x_t       = (const float*)d_in[0];
    const float* fast_prev = (const float*)d_in[1];
    const float* W_enc     = (const float*)d_in[2];
    const float* b_enc     = (const float*)d_in[3];
    const float* W_upd     = (const float*)d_in[4];
    const float* b_upd     = (const float*)d_in[5];
    const float* W_ro      = (const float*)d_in[6];
    const float* b_ro      = (const float*)d_in[7];
    float* out = (float*)d_out;

    // 2048 blocks x 1 wave, 1 element per wave -> 2 waves/SIMD resident
    fwp_kernel<<<2048, 64, 0, stream>>>(x_t, fast_prev, W_enc, b_enc,
                                        W_upd, b_upd, W_ro, b_ro,
                                        out /*y*/, out + 2048 /*fast_next*/);
}